// Round 2
// baseline (696.859 us; speedup 1.0000x reference)
//
#include <hip/hip_runtime.h>

#define UNITS 16
#define DIMS 272            // 16 + 16*16 floats per row
// 68 float4 per row: lanes 0..63 take #0..63, lanes 0..3 take tail #64..67

__global__ __launch_bounds__(256) void linear_pair_gemv(
    const float* __restrict__ in,     // [N, 272] row-major
    const float* __restrict__ kern,   // [16]
    const float* __restrict__ w1p,    // [1]
    const float* __restrict__ w2p,    // [1]
    const float* __restrict__ biasp,  // [1]
    float* __restrict__ out,          // [N]
    int N)
{
    __shared__ __align__(16) float sw[DIMS];

    const int t = threadIdx.x;

    // ---- build the 272 weights in LDS (once per block) ----
    {
        const float w1 = w1p[0];
        const float w2 = w2p[0];
        for (int j = t; j < DIMS; j += 256) {
            float v;
            if (j < UNITS) {
                v = kern[j];
            } else {
                const int p  = j - UNITS;     // 0..255
                const int x1 = p >> 4;
                const int x2 = p & 15;
                const int a1 = x1 >> 2, b1 = x1 & 3;
                const int a2 = x2 >> 2, b2 = x2 & 3;
                v = kern[4 * a1 + a2] * kern[4 * b1 + b2] * w1
                  + kern[4 * a1 + b2] * kern[4 * b1 + a2] * w2;
            }
            sw[j] = v;
        }
    }
    __syncthreads();

    const float bias = biasp[0];

    const int lane   = t & 63;
    const int wave   = t >> 6;                       // 0..3
    const int gwave  = blockIdx.x * 4 + wave;        // 0..8191
    const int stride = gridDim.x * 4 * 2;            // rows per sweep (pairs)

    // per-lane weight fragments, registers for the whole loop
    const float4* swv = (const float4*)sw;
    const float4 wv = swv[lane];
    float4 wt = make_float4(0.f, 0.f, 0.f, 0.f);
    const bool tailer = (lane < 4);
    if (tailer) wt = swv[64 + lane];

    for (int r = gwave * 2; r < N; r += stride) {
        const bool has2 = (r + 1 < N);
        const float4* rp0 = (const float4*)(in + (size_t)r * DIMS);
        const float4* rp1 = (const float4*)(in + (size_t)(has2 ? r + 1 : r) * DIMS);

        // issue all independent loads up front (MLP)
        float4 x0 = rp0[lane];
        float4 x1 = rp1[lane];
        float4 t0 = make_float4(0.f, 0.f, 0.f, 0.f);
        float4 t1 = make_float4(0.f, 0.f, 0.f, 0.f);
        if (tailer) {
            t0 = rp0[64 + lane];
            t1 = rp1[64 + lane];
        }

        float p0 = x0.x * wv.x + x0.y * wv.y + x0.z * wv.z + x0.w * wv.w;
        float p1 = x1.x * wv.x + x1.y * wv.y + x1.z * wv.z + x1.w * wv.w;
        if (tailer) {
            p0 += t0.x * wt.x + t0.y * wt.y + t0.z * wt.z + t0.w * wt.w;
            p1 += t1.x * wt.x + t1.y * wt.y + t1.z * wt.z + t1.w * wt.w;
        }

        // butterfly within each 32-half via ds_swizzle (masks 1..16), interleaved
        #pragma unroll
        for (int m = 1; m <= 16; m <<= 1) {
            p0 += __shfl_xor(p0, m, 64);
            p1 += __shfl_xor(p1, m, 64);
        }
        // cross-half combine -> wave-uniform scalars
        float s0 = __uint_as_float(__builtin_amdgcn_readlane(__float_as_uint(p0), 0))
                 + __uint_as_float(__builtin_amdgcn_readlane(__float_as_uint(p0), 32));
        float s1 = __uint_as_float(__builtin_amdgcn_readlane(__float_as_uint(p1), 0))
                 + __uint_as_float(__builtin_amdgcn_readlane(__float_as_uint(p1), 32));

        if (lane == 0) {
            if (has2) {
                *(float2*)(out + r) = make_float2(s0 + bias, s1 + bias); // r even -> 8B aligned
            } else {
                out[r] = s0 + bias;
            }
        }
    }
}

extern "C" void kernel_launch(void* const* d_in, const int* in_sizes, int n_in,
                              void* d_out, int out_size, void* d_ws, size_t ws_size,
                              hipStream_t stream) {
    const float* in    = (const float*)d_in[0];
    const float* kern  = (const float*)d_in[1];
    const float* w1p   = (const float*)d_in[2];
    const float* w2p   = (const float*)d_in[3];
    const float* biasp = (const float*)d_in[4];
    float* out         = (float*)d_out;

    const int N = in_sizes[0] / DIMS;   // 500000

    const int blocks = 2048;            // 8 blocks/CU -> 32 waves/CU (full occupancy)
    linear_pair_gemv<<<blocks, 256, 0, stream>>>(in, kern, w1p, w2p, biasp, out, N);
}